// Round 10
// baseline (10387.471 us; speedup 1.0000x reference)
//
#include <hip/hip_runtime.h>
#include <hip/hip_cooperative_groups.h>

namespace cg = cooperative_groups;

// ---------------------------------------------------------------------------
// MattingSolver CG on MI355X — round 20: R15 bodies + cooperative fused
// iteration loop, with runtime fallback to R15's two-dispatch loop.
//
// R19 (hand-rolled persistent barrier) core-dumped: manual co-residency /
// coherence assumptions are exactly what the platform guide says not to
// hand-roll. R20 uses the sanctioned mechanism:
//  * k_iter: 30 CG iterations, cg::this_grid().sync() between phases
//    (runtime-correct fences, validated residency).
//  * hipLaunchCooperativeKernel; on ANY error -> fall back to R15's
//    k_it1/k_it2 60-dispatch loop (worst case = proven 1781us).
//  * bodies/setup byte-for-byte R15 (8-wide int2 streams, PR fusion,
//    bucket-sorted Wm, fp32 S2p). __launch_bounds__(256,5): 1152 blocks
//    <= 1280 capacity for the cooperative validator.
// ws ~41.5 MB (identical to R15).
// ---------------------------------------------------------------------------

#define TPB 256

__device__ __forceinline__ float blockReduce256(float v) {
  #pragma unroll
  for (int o = 32; o > 0; o >>= 1) v += __shfl_down(v, o, 64);
  __shared__ float s[4];
  int lane = threadIdx.x & 63, wv = threadIdx.x >> 6;
  if (lane == 0) s[wv] = v;
  __syncthreads();
  return (threadIdx.x == 0) ? (s[0] + s[1] + s[2] + s[3]) : 0.f;
}

// vectors, diag, b, scal, CNT zero, sCNT zero, b.b  (grid: 3*Bn)
__global__ void k_init0(const float* __restrict__ KUw, const float* __restrict__ kToUconf,
                        const float* __restrict__ lmbda, const float* __restrict__ known,
                        const float* __restrict__ kToU,
                        float* __restrict__ diag_ku, float2* __restrict__ PR,
                        float* __restrict__ x,
                        int* __restrict__ CNT, int* __restrict__ sCNT,
                        float* __restrict__ scal, int N)
{
  int i = blockIdx.x * TPB + threadIdx.x;
  if (i < 80) scal[i] = 0.f;
  if (i < 576) sCNT[i] = 0;
  if (i < 3 * N) CNT[i] = 0;
  float red = 0.f;
  if (i < N) {
    float dk = KUw[i] * kToUconf[i] + lmbda[0] * known[i];
    diag_ku[i] = dk;
    float b = dk * kToU[i];
    PR[i] = make_float2(b, b);   // (p_old, r); first iter beta=0 -> p = r = b
    x[i] = 0.f;
    red = b * b;
  }
  float v = blockReduce256(red);
  if (threadIdx.x == 0) atomicAdd(&scal[0], v);
}

// in-place symmetrization: LOC_flows rows 0..35 <- 0.5*w*(F_ab+F_ba), a<b.
__global__ void k_prep(float* __restrict__ LOC_flows, const int* __restrict__ LOC_inInd,
                       const float* __restrict__ LOCw, int NLOC)
{
  int k = blockIdx.x * TPB + threadIdx.x;
  float Fl[81];
  #pragma unroll
  for (int m = 0; m < 81; ++m) Fl[m] = LOC_flows[(size_t)m * NLOC + k];
  float hw = 0.5f * LOCw[LOC_inInd[k]];
  int idx = 0;
  #pragma unroll
  for (int a = 0; a < 9; ++a)
    #pragma unroll
    for (int b = a + 1; b < 9; ++b) {
      LOC_flows[(size_t)idx * NLOC + k] = hw * (Fl[a * 9 + b] + Fl[b * 9 + a]);
      ++idx;
    }
}

// bucket-sort pass 1: count + ticket  (grid: Bl)
__global__ void k_sh(const int* __restrict__ LOC_inInd, int* __restrict__ sCNT,
                     unsigned short* __restrict__ sTick, int NLOC)
{
  int k = blockIdx.x * TPB + threadIdx.x;
  sTick[k] = (unsigned short)atomicAdd(&sCNT[LOC_inInd[k] >> 8], 1);
}

// bucket-sort pass 2: exclusive scan of 576 counters (1 block x 576)
__global__ void k_ss(int* __restrict__ sCNT)
{
  __shared__ int s[576];
  int v = sCNT[threadIdx.x];
  s[threadIdx.x] = v;
  __syncthreads();
  for (int o = 1; o < 576; o <<= 1) {
    int t = (threadIdx.x >= o) ? s[threadIdx.x - o] : 0;
    __syncthreads();
    s[threadIdx.x] += t;
    __syncthreads();
  }
  sCNT[threadIdx.x] = s[threadIdx.x] - v;
}

// bucket-sort pass 3: scatter perm + permuted LOC_inInd  (grid: Bl)
__global__ void k_sc(const int* __restrict__ LOC_inInd, const int* __restrict__ sCNT,
                     const unsigned short* __restrict__ sTick,
                     int* __restrict__ perm, int* __restrict__ LOC_inIndP, int NLOC)
{
  int k = blockIdx.x * TPB + threadIdx.x;
  int v = LOC_inInd[k];
  int pos = sCNT[v >> 8] + sTick[k];
  perm[pos] = k;
  LOC_inIndP[pos] = v;
}

// permuted copy of symmetrized S2: rows 36..71 col kp <- rows 0..35 col perm[kp]
__global__ void k_permS2(float* __restrict__ LOC_flows, const int* __restrict__ perm,
                         int NLOC)
{
  int kp = blockIdx.x * TPB + threadIdx.x;
  int k = perm[kp];
  #pragma unroll
  for (int m = 0; m < 36; ++m)
    LOC_flows[(size_t)(36 + m) * NLOC + kp] = LOC_flows[(size_t)m * NLOC + k];
}

// histograms + tickets  (grid: Bz + Bl + Bl)  — Wm branch uses permuted kp
__global__ void k_hist(const int* __restrict__ Wrow, const int* __restrict__ Wcol,
                       const int* __restrict__ LOC_inIndP, const int* __restrict__ width_p,
                       const int* __restrict__ IU_inInd, const int* __restrict__ IU_neighInd,
                       int* __restrict__ CNT,
                       unsigned short* __restrict__ tr, unsigned short* __restrict__ tc,
                       unsigned short* __restrict__ tU,
                       int NLOC, int N, int B0, int B1)
{
  int blk = blockIdx.x;
  if (blk < B0) {
    int e = blk * TPB + threadIdx.x;
    tr[e] = (unsigned short)atomicAdd(&CNT[Wrow[e]], 1);
    tc[e] = (unsigned short)atomicAdd(&CNT[N + Wcol[e]], 1);
  } else if (blk < B1) {                // Wm: (kp,a) by out-row, permuted order
    int kp = (blk - B0) * TPB + threadIdx.x;
    int wd = *width_p;
    int base = LOC_inIndP[kp];
    const int offs[9] = {-1 - wd, -1, -1 + wd, -wd, 0, wd, 1 - wd, 1, 1 + wd};
    #pragma unroll
    for (int a = 0; a < 9; ++a)
      tU[a * NLOC + kp] = (unsigned short)atomicAdd(&CNT[2 * N + base + offs[a]], 1);
  } else {                              // Wc: dirA k by r0, dirB (k,j) by c0
    int k = (blk - B1) * TPB + threadIdx.x;
    tU[14 * NLOC + k] = (unsigned short)atomicAdd(&CNT[2 * N + IU_inInd[k]], 1);
    #pragma unroll
    for (int j = 0; j < 5; ++j)
      tU[(9 + j) * NLOC + k] =
          (unsigned short)atomicAdd(&CNT[2 * N + IU_neighInd[k * 5 + j]], 1);
  }
}

// in-place exclusive scan (OFF==CNT)
__global__ void k_scan1(int* __restrict__ OFF, int* __restrict__ bsum, int tot)
{
  __shared__ int s[TPB];
  int gid = blockIdx.x * TPB + threadIdx.x;
  int v = (gid < tot) ? OFF[gid] : 0;
  s[threadIdx.x] = v;
  __syncthreads();
  #pragma unroll
  for (int o = 1; o < TPB; o <<= 1) {
    int t = (threadIdx.x >= o) ? s[threadIdx.x - o] : 0;
    __syncthreads();
    s[threadIdx.x] += t;
    __syncthreads();
  }
  if (gid < tot) OFF[gid] = s[threadIdx.x] - v;
  if (threadIdx.x == TPB - 1) bsum[blockIdx.x] = s[threadIdx.x];
}

__global__ void k_scan2(int* __restrict__ bsum, int nPerArr)  // 3 blocks x 1024
{
  __shared__ int s[1024];
  int base = blockIdx.x * nPerArr;
  int v = (threadIdx.x < nPerArr) ? bsum[base + threadIdx.x] : 0;
  s[threadIdx.x] = v;
  __syncthreads();
  for (int o = 1; o < 1024; o <<= 1) {
    int t = (threadIdx.x >= o) ? s[threadIdx.x - o] : 0;
    __syncthreads();
    s[threadIdx.x] += t;
    __syncthreads();
  }
  if (threadIdx.x < nPerArr) bsum[base + threadIdx.x] = s[threadIdx.x] - v;
}

__global__ void k_scan3(int* __restrict__ OFF, const int* __restrict__ bsum, int tot)
{
  int gid = blockIdx.x * TPB + threadIdx.x;
  if (gid < tot) OFF[gid] += bsum[blockIdx.x];
}

// atomic-free fill: pos = OFF[key] + ticket  (grid: Bz + Bl + Bl)
__global__ void k_fill(const float* __restrict__ CMw, const float* __restrict__ Wcm_data,
                       const int* __restrict__ Wrow, const int* __restrict__ Wcol,
                       const int* __restrict__ LOC_inIndP, const int* __restrict__ width_p,
                       const int* __restrict__ IU_inInd, const int* __restrict__ IU_neighInd,
                       const int* __restrict__ OFF,
                       const unsigned short* __restrict__ tr, const unsigned short* __restrict__ tc,
                       const unsigned short* __restrict__ tU,
                       int2* __restrict__ csrPk, int2* __restrict__ cscPk,
                       int* __restrict__ gU,
                       int NLOC, int N, int B0, int B1)
{
  int blk = blockIdx.x;
  if (blk < B0) {
    int e = blk * TPB + threadIdx.x;
    int row = Wrow[e], col = Wcol[e];
    int cv = __float_as_int(CMw[row] * Wcm_data[e]);
    csrPk[OFF[row] + tr[e]] = make_int2(col, cv);
    cscPk[OFF[N + col] + tc[e]] = make_int2(row, cv);
  } else if (blk < B1) {                // Wm permuted
    int kp = (blk - B0) * TPB + threadIdx.x;
    int wd = *width_p;
    int base = LOC_inIndP[kp];
    const int offs[9] = {-1 - wd, -1, -1 + wd, -wd, 0, wd, 1 - wd, 1, 1 + wd};
    #pragma unroll
    for (int a = 0; a < 9; ++a)
      gU[OFF[2 * N + base + offs[a]] + tU[a * NLOC + kp]] = a * NLOC + kp;
  } else {
    int k = (blk - B1) * TPB + threadIdx.x;
    gU[OFF[2 * N + IU_inInd[k]] + tU[14 * NLOC + k]] = 14 * NLOC + k;
    #pragma unroll
    for (int j = 0; j < 5; ++j)
      gU[OFF[2 * N + IU_neighInd[k * 5 + j]] + tU[(9 + j) * NLOC + k]] =
          (9 + j) * NLOC + k;
  }
}

// ---- phase-1 body (shared by fused + fallback) ----
__device__ __forceinline__ float phase1_body(
    int blk, const float2* __restrict__ PR,
    const float* __restrict__ S2p, const int* __restrict__ LOC_inIndP,
    const int* __restrict__ width_p,
    const float* __restrict__ IU_flows, const int* __restrict__ IU_inInd,
    const int* __restrict__ IU_neighInd, const float* __restrict__ IUw,
    const float* __restrict__ diag_ku, const int* __restrict__ OFF,
    const int2* __restrict__ csrPk, float* __restrict__ u_all,
    float* __restrict__ Lv, float* __restrict__ rs_cm,
    float beta, int NNZ, int NLOC, int N, int B0, int B1)
{
  float red = 0.f;
  if (blk < B0) {                       // Wm via symmetric pair coefficients
    int kp = blk * TPB + threadIdx.x;
    int wd = *width_p;
    int base = LOC_inIndP[kp];
    const int offs[9] = {-1 - wd, -1, -1 + wd, -wd, 0, wd, 1 - wd, 1, 1 + wd};
    float pv[9];
    #pragma unroll
    for (int a = 0; a < 9; ++a) {
      float2 pr = PR[base + offs[a]];
      pv[a] = __builtin_fmaf(beta, pr.x, pr.y);
    }
    float u[9] = {0.f, 0.f, 0.f, 0.f, 0.f, 0.f, 0.f, 0.f, 0.f};
    float qf = 0.f;
    int idx = 0;
    #pragma unroll
    for (int a = 0; a < 9; ++a)
      #pragma unroll
      for (int b = a + 1; b < 9; ++b) {
        float sv = S2p[(size_t)idx * NLOC + kp];
        ++idx;
        float d = pv[a] - pv[b];
        float tv = sv * d;
        u[a] += tv; u[b] -= tv;
        qf += tv * d;
      }
    #pragma unroll
    for (int a = 0; a < 9; ++a) u_all[a * NLOC + kp] = u[a];
    red = qf;
  } else if (blk < B1) {                // Wc
    int k = (blk - B0) * TPB + threadIdx.x;
    int r0 = IU_inInd[k];
    float hw = 0.5f * IUw[r0];
    float2 prr = PR[r0];
    float pr = __builtin_fmaf(beta, prr.x, prr.y);
    int c[5]; float w[5];
    #pragma unroll
    for (int j = 0; j < 5; ++j) {
      c[j] = IU_neighInd[k * 5 + j];
      w[j] = hw * IU_flows[k * 5 + j];
    }
    float pc[5];
    #pragma unroll
    for (int j = 0; j < 5; ++j) {
      float2 pp = PR[c[j]];
      pc[j] = __builtin_fmaf(beta, pp.x, pp.y);
    }
    float qf = 0.f, asum = 0.f;
    #pragma unroll
    for (int j = 0; j < 5; ++j) {
      float d = pr - pc[j];
      float uA = w[j] * d;
      u_all[(9 + j) * NLOC + k] = -uA;   // direction B (row c0)
      asum += uA;
      qf += uA * d;
    }
    u_all[14 * NLOC + k] = asum;          // direction A row-sum (row r0)
    red = qf;
  } else {                              // CSR: Lv = sum cv (p_i - p_c), 8-wide
    int i = (blk - B1) * TPB + threadIdx.x;
    float2 pri = PR[i];
    float pi = __builtin_fmaf(beta, pri.x, pri.y);
    int s = OFF[i];
    int e = (i == N - 1) ? NNZ : OFF[i + 1];
    float acc = 0.f, rs = 0.f;
    int q = s;
    for (; q + 8 <= e; q += 8) {
      int2 ed[8];
      #pragma unroll
      for (int m = 0; m < 8; ++m) ed[m] = csrPk[q + m];
      float g[8];
      #pragma unroll
      for (int m = 0; m < 8; ++m) {
        float2 pp = PR[ed[m].x];
        g[m] = __builtin_fmaf(beta, pp.x, pp.y);
      }
      #pragma unroll
      for (int m = 0; m < 8; ++m) {
        float cv = __int_as_float(ed[m].y);
        rs += cv;
        acc += cv * (pi - g[m]);
      }
    }
    for (; q + 4 <= e; q += 4) {
      int2 ed[4];
      #pragma unroll
      for (int m = 0; m < 4; ++m) ed[m] = csrPk[q + m];
      float g[4];
      #pragma unroll
      for (int m = 0; m < 4; ++m) {
        float2 pp = PR[ed[m].x];
        g[m] = __builtin_fmaf(beta, pp.x, pp.y);
      }
      #pragma unroll
      for (int m = 0; m < 4; ++m) {
        float cv = __int_as_float(ed[m].y);
        rs += cv;
        acc += cv * (pi - g[m]);
      }
    }
    for (; q < e; ++q) {
      int2 ed = csrPk[q];
      float cv = __int_as_float(ed.y);
      float2 pp = PR[ed.x];
      rs += cv;
      acc += cv * (pi - __builtin_fmaf(beta, pp.x, pp.y));
    }
    Lv[i] = acc;
    rs_cm[i] = rs;
    red = diag_ku[i] * pi * pi + acc * acc;
  }
  return red;
}

// ---- phase-2 body (shared): returns rn*rn contribution ----
__device__ __forceinline__ float phase2_body(
    int blk, float* __restrict__ x, float2* __restrict__ PR,
    const float* __restrict__ Lv, const float* __restrict__ rs_cm,
    const float* __restrict__ diag_ku, const int* __restrict__ OFF,
    const int2* __restrict__ cscPk, const int* __restrict__ gU,
    const float* __restrict__ u_all,
    float alpha, float beta, int NNZ, int NLOC, int N)
{
  int i = blk * TPB + threadIdx.x;
  float tg = 0.f;
  {
    int s0 = OFF[2 * N + i];
    int e0 = (i == N - 1) ? 15 * NLOC : OFF[2 * N + i + 1];
    int q = s0;
    for (; q + 8 <= e0; q += 8) {
      int g[8];
      #pragma unroll
      for (int m = 0; m < 8; ++m) g[m] = gU[q + m];
      float u[8];
      #pragma unroll
      for (int m = 0; m < 8; ++m) u[m] = u_all[g[m]];
      #pragma unroll
      for (int m = 0; m < 8; ++m) tg += u[m];
    }
    for (; q + 4 <= e0; q += 4) {
      int g[4];
      #pragma unroll
      for (int m = 0; m < 4; ++m) g[m] = gU[q + m];
      float u[4];
      #pragma unroll
      for (int m = 0; m < 4; ++m) u[m] = u_all[g[m]];
      #pragma unroll
      for (int m = 0; m < 4; ++m) tg += u[m];
    }
    for (; q < e0; ++q) tg += u_all[gU[q]];
  }
  float sc = 0.f;
  {
    int s0 = OFF[N + i];
    int e0 = (i == N - 1) ? NNZ : OFF[N + i + 1];
    int q = s0;
    for (; q + 8 <= e0; q += 8) {
      int2 ed[8];
      #pragma unroll
      for (int m = 0; m < 8; ++m) ed[m] = cscPk[q + m];
      float l[8];
      #pragma unroll
      for (int m = 0; m < 8; ++m) l[m] = Lv[ed[m].x];
      #pragma unroll
      for (int m = 0; m < 8; ++m) sc += __int_as_float(ed[m].y) * l[m];
    }
    for (; q + 4 <= e0; q += 4) {
      int2 ed[4];
      #pragma unroll
      for (int m = 0; m < 4; ++m) ed[m] = cscPk[q + m];
      float l[4];
      #pragma unroll
      for (int m = 0; m < 4; ++m) l[m] = Lv[ed[m].x];
      #pragma unroll
      for (int m = 0; m < 4; ++m) sc += __int_as_float(ed[m].y) * l[m];
    }
    for (; q < e0; ++q) {
      int2 ed = cscPk[q];
      sc += __int_as_float(ed.y) * Lv[ed.x];
    }
  }
  float2 pri = PR[i];
  float pi = __builtin_fmaf(beta, pri.x, pri.y);
  float Ap = diag_ku[i] * pi + rs_cm[i] * Lv[i] - sc + tg;
  x[i] += alpha * pi;
  float rn = pri.y - alpha * Ap;
  PR[i] = make_float2(pi, rn);          // (p_old, r) for next iteration
  return rn * rn;
}

// ---- fused 30-iteration CG loop: cooperative launch, grid.sync() ----
__global__ __launch_bounds__(TPB, 5) void k_iter(
    float* __restrict__ x, float2* __restrict__ PR,
    const float* __restrict__ S2p, const int* __restrict__ LOC_inIndP,
    const int* __restrict__ width_p,
    const float* __restrict__ IU_flows, const int* __restrict__ IU_inInd,
    const int* __restrict__ IU_neighInd, const float* __restrict__ IUw,
    const float* __restrict__ diag_ku, const int* __restrict__ OFF,
    const int2* __restrict__ csrPk, const int2* __restrict__ cscPk,
    const int* __restrict__ gU, float* __restrict__ u_all,
    float* __restrict__ Lv, float* __restrict__ rs_cm,
    float* __restrict__ scal,
    int NNZ, int NLOC, int N, int B0, int B1, int steps)
{
  cg::grid_group grid = cg::this_grid();
  int blk = blockIdx.x;
  for (int t = 0; t < steps; ++t) {
    float beta = (t == 0) ? 0.f : scal[t] / scal[t - 1];
    float red = phase1_body(blk, PR, S2p, LOC_inIndP, width_p,
                            IU_flows, IU_inInd, IU_neighInd, IUw,
                            diag_ku, OFF, csrPk, u_all, Lv, rs_cm,
                            beta, NNZ, NLOC, N, B0, B1);
    {
      float v = blockReduce256(red);
      if (threadIdx.x == 0) atomicAdd(&scal[40 + t], v);
    }
    grid.sync();
    if (blk < B1) {
      float alpha = scal[t] / scal[40 + t];
      float v2 = blockReduce256(
          phase2_body(blk, x, PR, Lv, rs_cm, diag_ku, OFF, cscPk, gU, u_all,
                      alpha, beta, NNZ, NLOC, N));
      if (threadIdx.x == 0) atomicAdd(&scal[t + 1], v2);
    }
    if (t + 1 < steps) grid.sync();
  }
}

// ---- fallback dispatch-loop kernels (R15, proven) ----
__global__ void k_it1(const float2* __restrict__ PR,
                      const float* __restrict__ S2p, const int* __restrict__ LOC_inIndP,
                      const int* __restrict__ width_p,
                      const float* __restrict__ IU_flows, const int* __restrict__ IU_inInd,
                      const int* __restrict__ IU_neighInd, const float* __restrict__ IUw,
                      const float* __restrict__ diag_ku,
                      const int* __restrict__ OFF, const int2* __restrict__ csrPk,
                      float* __restrict__ u_all,
                      float* __restrict__ Lv, float* __restrict__ rs_cm,
                      const float* __restrict__ rsN, const float* __restrict__ rsO, int first,
                      float* __restrict__ pAp_t,
                      int NNZ, int NLOC, int N, int B0, int B1)
{
  float beta = first ? 0.f : rsN[0] / rsO[0];
  float red = phase1_body(blockIdx.x, PR, S2p, LOC_inIndP, width_p,
                          IU_flows, IU_inInd, IU_neighInd, IUw,
                          diag_ku, OFF, csrPk, u_all, Lv, rs_cm,
                          beta, NNZ, NLOC, N, B0, B1);
  float v = blockReduce256(red);
  if (threadIdx.x == 0) atomicAdd(pAp_t, v);
}

__global__ void k_it2(float* __restrict__ x, float2* __restrict__ PR,
                      const float* __restrict__ Lv,
                      const float* __restrict__ rs_cm, const float* __restrict__ diag_ku,
                      const int* __restrict__ OFF,
                      const int2* __restrict__ cscPk,
                      const int* __restrict__ gU, const float* __restrict__ u_all,
                      const float* __restrict__ rs_t, const float* __restrict__ pAp_t,
                      const float* __restrict__ rsO, int first,
                      float* __restrict__ rs_t1,
                      int NNZ, int NLOC, int N)
{
  float alpha = rs_t[0] / pAp_t[0];
  float beta = first ? 0.f : rs_t[0] / rsO[0];
  float v = blockReduce256(
      phase2_body(blockIdx.x, x, PR, Lv, rs_cm, diag_ku, OFF, cscPk, gU, u_all,
                  alpha, beta, NNZ, NLOC, N));
  if (threadIdx.x == 0) atomicAdd(rs_t1, v);
}

extern "C" void kernel_launch(void* const* d_in, const int* in_sizes, int n_in,
                              void* d_out, int out_size, void* d_ws, size_t ws_size,
                              hipStream_t stream)
{
  const float* CMw       = (const float*)d_in[0];
  const float* LOCw      = (const float*)d_in[1];
  const float* IUw       = (const float*)d_in[2];
  const float* KUw       = (const float*)d_in[3];
  const float* lmbda     = (const float*)d_in[4];
  const float* kToUconf  = (const float*)d_in[5];
  const float* known     = (const float*)d_in[6];
  const float* kToU      = (const float*)d_in[7];
  const float* Wcm_data  = (const float*)d_in[8];
  float*       LOC_flows = (float*)d_in[9];      // overwritten in-place by k_prep
                                                 // + permuted S2 copy rows 36..71;
                                                 // harness restores d_in every launch
  const float* IU_flows  = (const float*)d_in[10];
  const int*   Wrow      = (const int*)d_in[11];
  const int*   Wcol      = (const int*)d_in[12];
  const int*   LOC_inInd = (const int*)d_in[13];
  const int*   IU_inInd  = (const int*)d_in[14];
  const int*   IU_neighInd = (const int*)d_in[15];
  const int*   width_p   = (const int*)d_in[16];
  const int CG_STEPS = 30;

  const int N    = in_sizes[0];      // 147456 (% 256 == 0)
  const int NNZ  = in_sizes[8];      // 1474560
  const int NLOC = in_sizes[13];     // 73728

  // ---- workspace layout, ~41.5 MB (identical to R15) ----
  float* x       = (float*)d_out;
  float2* PR     = (float2*)d_ws;                // N float2 (p_old, r)
  float* Lv      = (float*)(PR + (size_t)N);     // N
  float* rs_cm   = Lv + N;                       // N
  float* diag_ku = rs_cm + N;                    // N
  int2*  csrPk   = (int2*)(diag_ku + N);         // NNZ int2
  int2*  cscPk   = csrPk + (size_t)NNZ;          // NNZ int2
  int*   gU      = (int*)(cscPk + (size_t)NNZ);  // 15*NLOC
  int*   OFF     = gU + (size_t)15 * NLOC;       // 3N (in-place CNT -> OFF)
  unsigned short* tr = (unsigned short*)(OFF + (size_t)3 * N);  // NNZ u16
  unsigned short* tc = tr + (size_t)NNZ;         // NNZ u16
  unsigned short* tU = tc + (size_t)NNZ;         // 15*NLOC u16
  float* u_all   = (float*)tr;                   // 15*NLOC floats, aliases tickets
                                                 // (tickets dead after k_fill)
  int*   bsum    = (int*)(tU + (size_t)15 * NLOC);  // 3*(N/256)
  float* scal    = (float*)(bsum + 3 * (N / TPB));  // 80 floats
  int*   perm    = (int*)(scal + 80);            // NLOC
  int*   LOC_inIndP = perm + NLOC;               // NLOC
  int*   sCNT    = LOC_inIndP + NLOC;            // 576
  unsigned short* sTick = (unsigned short*)(sCNT + 576); // NLOC u16

  const int Bn = N / TPB;        // 576
  const int Bz = NNZ / TPB;      // 5760
  const int Bl = NLOC / TPB;     // 288
  const int Z3 = 3 * Bn;
  int NB = 2 * Bl + Bn;          // 1152

  k_init0<<<Z3, TPB, 0, stream>>>(KUw, kToUconf, lmbda, known, kToU,
                                  diag_ku, PR, x, OFF, sCNT, scal, N);
  k_prep<<<Bl, TPB, 0, stream>>>(LOC_flows, LOC_inInd, LOCw, NLOC);
  k_sh<<<Bl, TPB, 0, stream>>>(LOC_inInd, sCNT, sTick, NLOC);
  k_ss<<<1, 576, 0, stream>>>(sCNT);
  k_sc<<<Bl, TPB, 0, stream>>>(LOC_inInd, sCNT, sTick, perm, LOC_inIndP, NLOC);
  k_permS2<<<Bl, TPB, 0, stream>>>(LOC_flows, perm, NLOC);
  k_hist<<<Bz + 2 * Bl, TPB, 0, stream>>>(Wrow, Wcol, LOC_inIndP, width_p,
                                          IU_inInd, IU_neighInd, OFF,
                                          tr, tc, tU, NLOC, N, Bz, Bz + Bl);
  k_scan1<<<Z3, TPB, 0, stream>>>(OFF, bsum, 3 * N);
  k_scan2<<<3, 1024, 0, stream>>>(bsum, Bn);
  k_scan3<<<Z3, TPB, 0, stream>>>(OFF, bsum, 3 * N);
  k_fill<<<Bz + 2 * Bl, TPB, 0, stream>>>(CMw, Wcm_data, Wrow, Wcol,
                                          LOC_inIndP, width_p, IU_inInd, IU_neighInd,
                                          OFF, tr, tc, tU,
                                          csrPk, cscPk, gU,
                                          NLOC, N, Bz, Bz + Bl);

  const float* S2p = LOC_flows + (size_t)36 * NLOC;
  int B0 = Bl, B1 = 2 * Bl, steps = CG_STEPS;
  void* args[] = { &x, &PR, &S2p, &LOC_inIndP, &width_p,
                   &IU_flows, &IU_inInd, &IU_neighInd, &IUw,
                   &diag_ku, &OFF, &csrPk, &cscPk, &gU, &u_all,
                   &Lv, &rs_cm, &scal,
                   (void*)&NNZ, (void*)&NLOC, (void*)&N, &B0, &B1, &steps };
  hipError_t rc = hipLaunchCooperativeKernel((const void*)k_iter,
                                             dim3(NB), dim3(TPB),
                                             args, 0, stream);
  if (rc != hipSuccess) {
    (void)hipGetLastError();   // clear sticky error; fall back to R15 loop
    for (int t = 0; t < CG_STEPS; ++t) {
      const float* rsN = scal + t;
      const float* rsO = scal + (t == 0 ? 0 : t - 1);
      k_it1<<<2 * Bl + Bn, TPB, 0, stream>>>(
          PR, S2p, LOC_inIndP, width_p,
          IU_flows, IU_inInd, IU_neighInd, IUw,
          diag_ku, OFF, csrPk, u_all, Lv, rs_cm,
          rsN, rsO, (t == 0) ? 1 : 0, scal + 40 + t,
          NNZ, NLOC, N, Bl, 2 * Bl);
      k_it2<<<Bn, TPB, 0, stream>>>(
          x, PR, Lv, rs_cm, diag_ku, OFF, cscPk, gU, u_all,
          rsN, scal + 40 + t, rsO, (t == 0) ? 1 : 0, scal + t + 1,
          NNZ, NLOC, N);
    }
  }
}

// Round 11
// 1752.773 us; speedup vs baseline: 5.9263x; 5.9263x over previous
//
#include <hip/hip_runtime.h>

// ---------------------------------------------------------------------------
// MattingSolver CG on MI355X — round 21: R15 iterations (byte-identical) +
// atomic-free Wm setup via exact counting sort + arithmetic tickets.
//
// R20: cooperative grid.sync() = ~145us/sync on 1152 blocks -> fusion dead
// (10.4ms). R19 hand-rolled barrier: fault. Iteration bodies are locked at
// R15's proven shape (R11/R12/R13/R17/R18 all regressed or neutral).
// R21 takes R17's k_hist win WITHOUT R17's it2 loss:
//  * exact counting sort (R17-proven): H=CNT[3N..4N) histogram + sTick,
//    scan gives cum; scatter -> LOC_inIndP fully sorted.
//  * k_wminit: CNT[2N+j] = wmCnt[j] = sum_a H[j-offs[a]] (raw H, no atomics)
//    BEFORE k_hist -> Wc tickets start above Wm block.
//  * k_hist Wm branch DELETED (-663K of 4.05M atomics, -21MB write-through).
//  * k_fill Wm branch: slot = OFF[2N+j] + T(a) + (kp - cum[base]) where
//    T(a) = sum_{a'<a} hh[diff] from a 5x5 cum-difference table (L2-hot).
//    Bijective per row: plane blocks partition [0,wmCnt), ranks partition
//    each block. gU content (a*NLOC+kp) unchanged -> it2 identical to R15.
// ws ~40.8 MB.
// ---------------------------------------------------------------------------

#define TPB 256

__device__ __forceinline__ float blockReduce256(float v) {
  #pragma unroll
  for (int o = 32; o > 0; o >>= 1) v += __shfl_down(v, o, 64);
  __shared__ float s[4];
  int lane = threadIdx.x & 63, wv = threadIdx.x >> 6;
  if (lane == 0) s[wv] = v;
  __syncthreads();
  return (threadIdx.x == 0) ? (s[0] + s[1] + s[2] + s[3]) : 0.f;
}

// vectors, diag, b, scal, CNT zero (4N), b.b  (grid: 4*Bn)
__global__ void k_init0(const float* __restrict__ KUw, const float* __restrict__ kToUconf,
                        const float* __restrict__ lmbda, const float* __restrict__ known,
                        const float* __restrict__ kToU,
                        float* __restrict__ diag_ku, float2* __restrict__ PR,
                        float* __restrict__ x,
                        int* __restrict__ CNT, float* __restrict__ scal, int N)
{
  int i = blockIdx.x * TPB + threadIdx.x;
  if (i < 80) scal[i] = 0.f;
  if (i < 4 * N) CNT[i] = 0;
  float red = 0.f;
  if (i < N) {
    float dk = KUw[i] * kToUconf[i] + lmbda[0] * known[i];
    diag_ku[i] = dk;
    float b = dk * kToU[i];
    PR[i] = make_float2(b, b);   // (p_old, r); first iter beta=0 -> p = r = b
    x[i] = 0.f;
    red = b * b;
  }
  float v = blockReduce256(red);
  if (threadIdx.x == 0) atomicAdd(&scal[0], v);
}

// in-place symmetrization: LOC_flows rows 0..35 <- 0.5*w*(F_ab+F_ba), a<b.
// Thread k owns column k; harness restores d_in before every launch.
__global__ void k_prep(float* __restrict__ LOC_flows, const int* __restrict__ LOC_inInd,
                       const float* __restrict__ LOCw, int NLOC)
{
  int k = blockIdx.x * TPB + threadIdx.x;
  float Fl[81];
  #pragma unroll
  for (int m = 0; m < 81; ++m) Fl[m] = LOC_flows[(size_t)m * NLOC + k];
  float hw = 0.5f * LOCw[LOC_inInd[k]];
  int idx = 0;
  #pragma unroll
  for (int a = 0; a < 9; ++a)
    #pragma unroll
    for (int b = a + 1; b < 9; ++b) {
      LOC_flows[(size_t)idx * NLOC + k] = hw * (Fl[a * 9 + b] + Fl[b * 9 + a]);
      ++idx;
    }
}

// counting-sort pass 1: value histogram (H = CNT[3N..4N)) + ticket (grid: Bl)
__global__ void k_sh(const int* __restrict__ LOC_inInd, int* __restrict__ CNT,
                     unsigned short* __restrict__ sTick, int N, int NLOC)
{
  int k = blockIdx.x * TPB + threadIdx.x;
  sTick[k] = (unsigned short)atomicAdd(&CNT[3 * N + LOC_inInd[k]], 1);
}

// CNT[2N+j] = wmCnt[j] = sum_a H[j - offs[a]]  (raw H, pre-scan; grid: Bn)
// Must run after k_sh and before k_hist (Wc atomics add on top).
__global__ void k_wminit(int* __restrict__ CNT, const int* __restrict__ width_p, int N)
{
  int j = blockIdx.x * TPB + threadIdx.x;
  int wd = *width_p;
  const int offs[9] = {-1 - wd, -1, -1 + wd, -wd, 0, wd, 1 - wd, 1, 1 + wd};
  int s = 0;
  #pragma unroll
  for (int a = 0; a < 9; ++a) {
    int v = j - offs[a];
    if (v >= 0 && v < N) s += CNT[3 * N + v];
  }
  CNT[2 * N + j] = s;
}

// histograms + tickets  (grid: Bz + Bl)  — CM + Wc only (Wm atomic-free)
__global__ void k_hist(const int* __restrict__ Wrow, const int* __restrict__ Wcol,
                       const int* __restrict__ IU_inInd, const int* __restrict__ IU_neighInd,
                       int* __restrict__ CNT,
                       unsigned short* __restrict__ tr, unsigned short* __restrict__ tc,
                       unsigned short* __restrict__ tU,
                       int NLOC, int N, int B0)
{
  int blk = blockIdx.x;
  if (blk < B0) {
    int e = blk * TPB + threadIdx.x;
    tr[e] = (unsigned short)atomicAdd(&CNT[Wrow[e]], 1);
    tc[e] = (unsigned short)atomicAdd(&CNT[N + Wcol[e]], 1);
  } else {                              // Wc: dirA k by r0, dirB (k,j) by c0
    int k = (blk - B0) * TPB + threadIdx.x;
    tU[5 * NLOC + k] = (unsigned short)atomicAdd(&CNT[2 * N + IU_inInd[k]], 1);
    #pragma unroll
    for (int j = 0; j < 5; ++j)
      tU[j * NLOC + k] =
          (unsigned short)atomicAdd(&CNT[2 * N + IU_neighInd[k * 5 + j]], 1);
  }
}

// in-place exclusive scan (OFF==CNT); 4 N-length sections scanned independently
__global__ void k_scan1(int* __restrict__ OFF, int* __restrict__ bsum, int tot)
{
  __shared__ int s[TPB];
  int gid = blockIdx.x * TPB + threadIdx.x;
  int v = (gid < tot) ? OFF[gid] : 0;
  s[threadIdx.x] = v;
  __syncthreads();
  #pragma unroll
  for (int o = 1; o < TPB; o <<= 1) {
    int t = (threadIdx.x >= o) ? s[threadIdx.x - o] : 0;
    __syncthreads();
    s[threadIdx.x] += t;
    __syncthreads();
  }
  if (gid < tot) OFF[gid] = s[threadIdx.x] - v;
  if (threadIdx.x == TPB - 1) bsum[blockIdx.x] = s[threadIdx.x];
}

__global__ void k_scan2(int* __restrict__ bsum, int nPerArr)  // 4 blocks x 1024
{
  __shared__ int s[1024];
  int base = blockIdx.x * nPerArr;
  int v = (threadIdx.x < nPerArr) ? bsum[base + threadIdx.x] : 0;
  s[threadIdx.x] = v;
  __syncthreads();
  for (int o = 1; o < 1024; o <<= 1) {
    int t = (threadIdx.x >= o) ? s[threadIdx.x - o] : 0;
    __syncthreads();
    s[threadIdx.x] += t;
    __syncthreads();
  }
  if (threadIdx.x < nPerArr) bsum[base + threadIdx.x] = s[threadIdx.x] - v;
}

__global__ void k_scan3(int* __restrict__ OFF, const int* __restrict__ bsum, int tot)
{
  int gid = blockIdx.x * TPB + threadIdx.x;
  if (gid < tot) OFF[gid] += bsum[blockIdx.x];
}

// counting-sort scatter (after scan): fully sorted, stable  (grid: Bl)
__global__ void k_sc(const int* __restrict__ LOC_inInd, const int* __restrict__ OFF,
                     const unsigned short* __restrict__ sTick,
                     int* __restrict__ perm, int* __restrict__ LOC_inIndP,
                     int N, int NLOC)
{
  int k = blockIdx.x * TPB + threadIdx.x;
  int v = LOC_inInd[k];
  int pos = OFF[3 * N + v] + sTick[k];
  perm[pos] = k;
  LOC_inIndP[pos] = v;
}

// permuted copy of symmetrized S2: rows 36..71 col kp <- rows 0..35 col perm[kp]
__global__ void k_permS2(float* __restrict__ LOC_flows, const int* __restrict__ perm,
                         int NLOC)
{
  int kp = blockIdx.x * TPB + threadIdx.x;
  int k = perm[kp];
  #pragma unroll
  for (int m = 0; m < 36; ++m)
    LOC_flows[(size_t)(36 + m) * NLOC + kp] = LOC_flows[(size_t)m * NLOC + k];
}

// fill: CM via tickets; Wm via ARITHMETIC tickets (cum); Wc via tickets.
// grid: Bz + Bl + Bl
__global__ void k_fill(const float* __restrict__ CMw, const float* __restrict__ Wcm_data,
                       const int* __restrict__ Wrow, const int* __restrict__ Wcol,
                       const int* __restrict__ LOC_inIndP, const int* __restrict__ width_p,
                       const int* __restrict__ IU_inInd, const int* __restrict__ IU_neighInd,
                       const int* __restrict__ OFF,
                       const unsigned short* __restrict__ tr, const unsigned short* __restrict__ tc,
                       const unsigned short* __restrict__ tU,
                       int2* __restrict__ csrPk, int2* __restrict__ cscPk,
                       int* __restrict__ gU,
                       int NLOC, int N, int B0, int B1)
{
  int blk = blockIdx.x;
  if (blk < B0) {
    int e = blk * TPB + threadIdx.x;
    int row = Wrow[e], col = Wcol[e];
    int cv = __float_as_int(CMw[row] * Wcm_data[e]);
    csrPk[OFF[row] + tr[e]] = make_int2(col, cv);
    cscPk[OFF[N + col] + tc[e]] = make_int2(row, cv);
  } else if (blk < B1) {                // Wm: arithmetic tickets
    int kp = (blk - B0) * TPB + threadIdx.x;
    int wd = *width_p;
    int base = LOC_inIndP[kp];
    const int* cum = OFF + 3 * N;       // scanned base histogram; cum[N] := NLOC
    int rank = kp - cum[base];
    // hh[dr][dc] = run length of bases equal to base + (dr-2)*wd + (dc-2)
    int hh[5][5];
    #pragma unroll
    for (int dr = 0; dr < 5; ++dr) {
      int c[6];
      #pragma unroll
      for (int m = 0; m < 6; ++m) {
        int v = base + (dr - 2) * wd + (m - 2);
        c[m] = (v <= 0) ? 0 : ((v >= N) ? NLOC : cum[v]);
      }
      #pragma unroll
      for (int m = 0; m < 5; ++m) hh[dr][m] = c[m + 1] - c[m];
    }
    const int CAv[9] = {-1, -1, -1, 0, 0, 0, 1, 1, 1};   // offs[a] = CA + RA*wd
    const int RAv[9] = {-1, 0, 1, -1, 0, 1, -1, 0, 1};
    #pragma unroll
    for (int a = 0; a < 9; ++a) {
      int T = 0;
      #pragma unroll
      for (int ap = 0; ap < a; ++ap)
        T += hh[RAv[a] - RAv[ap] + 2][CAv[a] - CAv[ap] + 2];
      int j = base + CAv[a] + RAv[a] * wd;
      gU[OFF[2 * N + j] + T + rank] = a * NLOC + kp;
    }
  } else {                              // Wc ticketed (tickets start at wmCnt[j])
    int k = (blk - B1) * TPB + threadIdx.x;
    gU[OFF[2 * N + IU_inInd[k]] + tU[5 * NLOC + k]] = 14 * NLOC + k;
    #pragma unroll
    for (int j = 0; j < 5; ++j)
      gU[OFF[2 * N + IU_neighInd[k * 5 + j]] + tU[j * NLOC + k]] =
          (9 + j) * NLOC + k;
  }
}

// pass 1: p = fma(beta, p_old, r) on the fly; Wm (sorted) / Wc -> u_all;
// CSR Lv/rs_cm (8-wide); pAp.  grid: Bl + Bl + Bn   (byte-identical to R15)
__global__ void k_it1(const float2* __restrict__ PR,
                      const float* __restrict__ S2p, const int* __restrict__ LOC_inIndP,
                      const int* __restrict__ width_p,
                      const float* __restrict__ IU_flows, const int* __restrict__ IU_inInd,
                      const int* __restrict__ IU_neighInd, const float* __restrict__ IUw,
                      const float* __restrict__ diag_ku,
                      const int* __restrict__ OFF, const int2* __restrict__ csrPk,
                      float* __restrict__ u_all,
                      float* __restrict__ Lv, float* __restrict__ rs_cm,
                      const float* __restrict__ rsN, const float* __restrict__ rsO, int first,
                      float* __restrict__ pAp_t,
                      int NNZ, int NLOC, int N, int B0, int B1)
{
  int blk = blockIdx.x;
  float beta = first ? 0.f : rsN[0] / rsO[0];
  float red = 0.f;
  if (blk < B0) {                       // Wm via symmetric pair coefficients
    int kp = blk * TPB + threadIdx.x;
    int wd = *width_p;
    int base = LOC_inIndP[kp];
    const int offs[9] = {-1 - wd, -1, -1 + wd, -wd, 0, wd, 1 - wd, 1, 1 + wd};
    float pv[9];
    #pragma unroll
    for (int a = 0; a < 9; ++a) {
      float2 pr = PR[base + offs[a]];
      pv[a] = __builtin_fmaf(beta, pr.x, pr.y);
    }
    float u[9] = {0.f, 0.f, 0.f, 0.f, 0.f, 0.f, 0.f, 0.f, 0.f};
    float qf = 0.f;
    int idx = 0;
    #pragma unroll
    for (int a = 0; a < 9; ++a)
      #pragma unroll
      for (int b = a + 1; b < 9; ++b) {
        float sv = S2p[(size_t)idx * NLOC + kp];
        ++idx;
        float d = pv[a] - pv[b];
        float t = sv * d;
        u[a] += t; u[b] -= t;
        qf += t * d;
      }
    #pragma unroll
    for (int a = 0; a < 9; ++a) u_all[a * NLOC + kp] = u[a];
    red = qf;
  } else if (blk < B1) {                // Wc
    int k = (blk - B0) * TPB + threadIdx.x;
    int r0 = IU_inInd[k];
    float hw = 0.5f * IUw[r0];
    float2 prr = PR[r0];
    float pr = __builtin_fmaf(beta, prr.x, prr.y);
    int c[5]; float w[5];
    #pragma unroll
    for (int j = 0; j < 5; ++j) {
      c[j] = IU_neighInd[k * 5 + j];
      w[j] = hw * IU_flows[k * 5 + j];
    }
    float pc[5];
    #pragma unroll
    for (int j = 0; j < 5; ++j) {
      float2 pp = PR[c[j]];
      pc[j] = __builtin_fmaf(beta, pp.x, pp.y);
    }
    float qf = 0.f, asum = 0.f;
    #pragma unroll
    for (int j = 0; j < 5; ++j) {
      float d = pr - pc[j];
      float uA = w[j] * d;
      u_all[(9 + j) * NLOC + k] = -uA;   // direction B (row c0)
      asum += uA;
      qf += uA * d;
    }
    u_all[14 * NLOC + k] = asum;          // direction A row-sum (row r0)
    red = qf;
  } else {                              // CSR: Lv = sum cv (p_i - p_c), 8-wide
    int i = (blk - B1) * TPB + threadIdx.x;
    float2 pri = PR[i];
    float pi = __builtin_fmaf(beta, pri.x, pri.y);
    int s = OFF[i];
    int e = (i == N - 1) ? NNZ : OFF[i + 1];
    float acc = 0.f, rs = 0.f;
    int q = s;
    for (; q + 8 <= e; q += 8) {
      int2 ed[8];
      #pragma unroll
      for (int m = 0; m < 8; ++m) ed[m] = csrPk[q + m];
      float g[8];
      #pragma unroll
      for (int m = 0; m < 8; ++m) {
        float2 pp = PR[ed[m].x];
        g[m] = __builtin_fmaf(beta, pp.x, pp.y);
      }
      #pragma unroll
      for (int m = 0; m < 8; ++m) {
        float cv = __int_as_float(ed[m].y);
        rs += cv;
        acc += cv * (pi - g[m]);
      }
    }
    for (; q + 4 <= e; q += 4) {
      int2 ed[4];
      #pragma unroll
      for (int m = 0; m < 4; ++m) ed[m] = csrPk[q + m];
      float g[4];
      #pragma unroll
      for (int m = 0; m < 4; ++m) {
        float2 pp = PR[ed[m].x];
        g[m] = __builtin_fmaf(beta, pp.x, pp.y);
      }
      #pragma unroll
      for (int m = 0; m < 4; ++m) {
        float cv = __int_as_float(ed[m].y);
        rs += cv;
        acc += cv * (pi - g[m]);
      }
    }
    for (; q < e; ++q) {
      int2 ed = csrPk[q];
      float cv = __int_as_float(ed.y);
      float2 pp = PR[ed.x];
      rs += cv;
      acc += cv * (pi - __builtin_fmaf(beta, pp.x, pp.y));
    }
    Lv[i] = acc;
    rs_cm[i] = rs;
    red = diag_ku[i] * pi * pi + acc * acc;
  }
  float v = blockReduce256(red);
  if (threadIdx.x == 0) atomicAdd(pAp_t, v);
}

// pass 2: Ap = diag p + rs_cm Lv - csc_pull(Lv) + u-pull; x += alpha p;
// PR <- (p, r_new); r.r   (grid: Bn; byte-identical to R15)
__global__ void k_it2(float* __restrict__ x, float2* __restrict__ PR,
                      const float* __restrict__ Lv,
                      const float* __restrict__ rs_cm, const float* __restrict__ diag_ku,
                      const int* __restrict__ OFF,
                      const int2* __restrict__ cscPk,
                      const int* __restrict__ gU, const float* __restrict__ u_all,
                      const float* __restrict__ rs_t, const float* __restrict__ pAp_t,
                      const float* __restrict__ rsO, int first,
                      float* __restrict__ rs_t1,
                      int NNZ, int NLOC, int N)
{
  int i = blockIdx.x * TPB + threadIdx.x;
  float alpha = rs_t[0] / pAp_t[0];
  float beta = first ? 0.f : rs_t[0] / rsO[0];
  // unified u-pull (Wm + WcA + WcB), 8/4/1-wide
  float tg = 0.f;
  {
    int s0 = OFF[2 * N + i];
    int e0 = (i == N - 1) ? 15 * NLOC : OFF[2 * N + i + 1];
    int q = s0;
    for (; q + 8 <= e0; q += 8) {
      int g[8];
      #pragma unroll
      for (int m = 0; m < 8; ++m) g[m] = gU[q + m];
      float u[8];
      #pragma unroll
      for (int m = 0; m < 8; ++m) u[m] = u_all[g[m]];
      #pragma unroll
      for (int m = 0; m < 8; ++m) tg += u[m];
    }
    for (; q + 4 <= e0; q += 4) {
      int g[4];
      #pragma unroll
      for (int m = 0; m < 4; ++m) g[m] = gU[q + m];
      float u[4];
      #pragma unroll
      for (int m = 0; m < 4; ++m) u[m] = u_all[g[m]];
      #pragma unroll
      for (int m = 0; m < 4; ++m) tg += u[m];
    }
    for (; q < e0; ++q) tg += u_all[gU[q]];
  }
  // CM: W^T Lv via CSC, 8/4/1-wide
  float sc = 0.f;
  {
    int s0 = OFF[N + i];
    int e0 = (i == N - 1) ? NNZ : OFF[N + i + 1];
    int q = s0;
    for (; q + 8 <= e0; q += 8) {
      int2 ed[8];
      #pragma unroll
      for (int m = 0; m < 8; ++m) ed[m] = cscPk[q + m];
      float l[8];
      #pragma unroll
      for (int m = 0; m < 8; ++m) l[m] = Lv[ed[m].x];
      #pragma unroll
      for (int m = 0; m < 8; ++m) sc += __int_as_float(ed[m].y) * l[m];
    }
    for (; q + 4 <= e0; q += 4) {
      int2 ed[4];
      #pragma unroll
      for (int m = 0; m < 4; ++m) ed[m] = cscPk[q + m];
      float l[4];
      #pragma unroll
      for (int m = 0; m < 4; ++m) l[m] = Lv[ed[m].x];
      #pragma unroll
      for (int m = 0; m < 4; ++m) sc += __int_as_float(ed[m].y) * l[m];
    }
    for (; q < e0; ++q) {
      int2 ed = cscPk[q];
      sc += __int_as_float(ed.y) * Lv[ed.x];
    }
  }
  float2 pri = PR[i];
  float pi = __builtin_fmaf(beta, pri.x, pri.y);
  float Ap = diag_ku[i] * pi + rs_cm[i] * Lv[i] - sc + tg;
  x[i] += alpha * pi;
  float rn = pri.y - alpha * Ap;
  PR[i] = make_float2(pi, rn);          // (p_old, r) for next iteration
  float v = blockReduce256(rn * rn);
  if (threadIdx.x == 0) atomicAdd(rs_t1, v);
}

extern "C" void kernel_launch(void* const* d_in, const int* in_sizes, int n_in,
                              void* d_out, int out_size, void* d_ws, size_t ws_size,
                              hipStream_t stream)
{
  const float* CMw       = (const float*)d_in[0];
  const float* LOCw      = (const float*)d_in[1];
  const float* IUw       = (const float*)d_in[2];
  const float* KUw       = (const float*)d_in[3];
  const float* lmbda     = (const float*)d_in[4];
  const float* kToUconf  = (const float*)d_in[5];
  const float* known     = (const float*)d_in[6];
  const float* kToU      = (const float*)d_in[7];
  const float* Wcm_data  = (const float*)d_in[8];
  float*       LOC_flows = (float*)d_in[9];      // overwritten in-place by k_prep
                                                 // + permuted S2 copy rows 36..71;
                                                 // harness restores d_in every launch
  const float* IU_flows  = (const float*)d_in[10];
  const int*   Wrow      = (const int*)d_in[11];
  const int*   Wcol      = (const int*)d_in[12];
  const int*   LOC_inInd = (const int*)d_in[13];
  const int*   IU_inInd  = (const int*)d_in[14];
  const int*   IU_neighInd = (const int*)d_in[15];
  const int*   width_p   = (const int*)d_in[16];
  const int CG_STEPS = 30;

  const int N    = in_sizes[0];      // 147456 (% 256 == 0)
  const int NNZ  = in_sizes[8];      // 1474560
  const int NLOC = in_sizes[13];     // 73728

  // ---- workspace layout, ~40.8 MB ----
  float* x       = (float*)d_out;
  float2* PR     = (float2*)d_ws;                // N float2 (p_old, r)
  float* Lv      = (float*)(PR + (size_t)N);     // N
  float* rs_cm   = Lv + N;                       // N
  float* diag_ku = rs_cm + N;                    // N
  int2*  csrPk   = (int2*)(diag_ku + N);         // NNZ int2
  int2*  cscPk   = csrPk + (size_t)NNZ;          // NNZ int2
  int*   gU      = (int*)(cscPk + (size_t)NNZ);  // 15*NLOC
  int*   OFF     = gU + (size_t)15 * NLOC;       // 4N (CNT -> OFF; sec3 = cum)
  unsigned short* tr = (unsigned short*)(OFF + (size_t)4 * N);  // NNZ u16
  unsigned short* tc = tr + (size_t)NNZ;         // NNZ u16
  unsigned short* tU = tc + (size_t)NNZ;         // 6*NLOC u16 (Wc only)
  float* u_all   = (float*)tr;                   // 15*NLOC floats, aliases tickets
                                                 // (tickets dead after k_fill)
  int*   bsum    = (int*)(tU + (size_t)6 * NLOC);   // 4*(N/256)
  float* scal    = (float*)(bsum + 4 * (N / TPB));  // 80 floats
  int*   perm    = (int*)(scal + 80);            // NLOC
  int*   LOC_inIndP = perm + NLOC;               // NLOC
  unsigned short* sTick = (unsigned short*)(LOC_inIndP + NLOC); // NLOC u16

  const int Bn = N / TPB;        // 576
  const int Bz = NNZ / TPB;      // 5760
  const int Bl = NLOC / TPB;     // 288
  const int Z4 = 4 * Bn;

  k_init0<<<Z4, TPB, 0, stream>>>(KUw, kToUconf, lmbda, known, kToU,
                                  diag_ku, PR, x, OFF, scal, N);
  k_prep<<<Bl, TPB, 0, stream>>>(LOC_flows, LOC_inInd, LOCw, NLOC);
  k_sh<<<Bl, TPB, 0, stream>>>(LOC_inInd, OFF, sTick, N, NLOC);
  k_wminit<<<Bn, TPB, 0, stream>>>(OFF, width_p, N);
  k_hist<<<Bz + Bl, TPB, 0, stream>>>(Wrow, Wcol, IU_inInd, IU_neighInd, OFF,
                                      tr, tc, tU, NLOC, N, Bz);
  k_scan1<<<Z4, TPB, 0, stream>>>(OFF, bsum, 4 * N);
  k_scan2<<<4, 1024, 0, stream>>>(bsum, Bn);
  k_scan3<<<Z4, TPB, 0, stream>>>(OFF, bsum, 4 * N);
  k_sc<<<Bl, TPB, 0, stream>>>(LOC_inInd, OFF, sTick, perm, LOC_inIndP, N, NLOC);
  k_permS2<<<Bl, TPB, 0, stream>>>(LOC_flows, perm, NLOC);
  k_fill<<<Bz + 2 * Bl, TPB, 0, stream>>>(CMw, Wcm_data, Wrow, Wcol,
                                          LOC_inIndP, width_p, IU_inInd, IU_neighInd,
                                          OFF, tr, tc, tU,
                                          csrPk, cscPk, gU,
                                          NLOC, N, Bz, Bz + Bl);

  const float* S2p = LOC_flows + (size_t)36 * NLOC;
  for (int t = 0; t < CG_STEPS; ++t) {
    const float* rsN = scal + t;
    const float* rsO = scal + (t == 0 ? 0 : t - 1);
    k_it1<<<2 * Bl + Bn, TPB, 0, stream>>>(
        PR, S2p, LOC_inIndP, width_p,
        IU_flows, IU_inInd, IU_neighInd, IUw,
        diag_ku, OFF, csrPk, u_all, Lv, rs_cm,
        rsN, rsO, (t == 0) ? 1 : 0, scal + 40 + t,
        NNZ, NLOC, N, Bl, 2 * Bl);
    k_it2<<<Bn, TPB, 0, stream>>>(
        x, PR, Lv, rs_cm, diag_ku, OFF, cscPk, gU, u_all,
        rsN, scal + 40 + t, rsO, (t == 0) ? 1 : 0, scal + t + 1,
        NNZ, NLOC, N);
  }
}